// Round 5
// baseline (1115.020 us; speedup 1.0000x reference)
//
#include <hip/hip_runtime.h>
#include <hip/hip_fp16.h>
#include <math.h>

__device__ __forceinline__ void unpack8(uint4 u, float* f) {
    union { uint4 u; __half2 h2[4]; } U; U.u = u;
    float2 a = __half22float2(U.h2[0]);
    float2 b = __half22float2(U.h2[1]);
    float2 c = __half22float2(U.h2[2]);
    float2 d = __half22float2(U.h2[3]);
    f[0] = a.x; f[1] = a.y; f[2] = b.x; f[3] = b.y;
    f[4] = c.x; f[5] = c.y; f[6] = d.x; f[7] = d.y;
}

// ---------- preprocessing ----------
__global__ void k_init_deg(int* deg, int N) {
    int i = blockIdx.x * blockDim.x + threadIdx.x;
    if (i < N) deg[i] = 1;  // self loop
}

__global__ void k_count(const int* __restrict__ dst, int* deg, int E) {
    int i = blockIdx.x * blockDim.x + threadIdx.x;
    if (i < E) atomicAdd(&deg[dst[i]], 1);
}

__global__ void k_dis(const int* __restrict__ deg, float* dis, int N) {
    int i = blockIdx.x * blockDim.x + threadIdx.x;
    if (i < N) dis[i] = rsqrtf((float)deg[i]);  // deg >= 1 always
}

// exclusive scan of deg[0..N) -> offs[0..N], offs[N] = total
__global__ void k_scan1(const int* __restrict__ deg, int* part, int N) {
    int base = blockIdx.x * 1024;
    int tid = threadIdx.x;
    int s = 0;
#pragma unroll
    for (int j = 0; j < 4; ++j) {
        int idx = base + tid * 4 + j;
        if (idx < N) s += deg[idx];
    }
    __shared__ int sm[256];
    sm[tid] = s;
    __syncthreads();
    for (int off = 128; off > 0; off >>= 1) {
        if (tid < off) sm[tid] += sm[tid + off];
        __syncthreads();
    }
    if (tid == 0) part[blockIdx.x] = sm[0];
}

__global__ void k_scan2(int* part, int nb, int* offs, int N) {
    if (blockIdx.x == 0 && threadIdx.x == 0) {
        int run = 0;
        for (int b = 0; b < nb; ++b) { int t = part[b]; part[b] = run; run += t; }
        offs[N] = run;
    }
}

__global__ void k_scan3(const int* __restrict__ deg, const int* __restrict__ part,
                        int* offs, int N) {
    __shared__ int sm[256];
    int base = blockIdx.x * 1024;
    int tid = threadIdx.x;
    int a[4];
    int s = 0;
#pragma unroll
    for (int j = 0; j < 4; ++j) {
        int idx = base + tid * 4 + j;
        a[j] = (idx < N) ? deg[idx] : 0;
        s += a[j];
    }
    sm[tid] = s;
    __syncthreads();
    for (int off = 1; off < 256; off <<= 1) {
        int v = (tid >= off) ? sm[tid - off] : 0;
        __syncthreads();
        sm[tid] += v;
        __syncthreads();
    }
    int excl = sm[tid] - s + part[blockIdx.x];
#pragma unroll
    for (int j = 0; j < 4; ++j) {
        int idx = base + tid * 4 + j;
        if (idx < N) offs[idx] = excl;
        excl += a[j];
    }
}

__global__ void k_fill(const int* __restrict__ ei, int E, int N,
                       const int* __restrict__ offs, int* cursor, int* csr) {
    int i = blockIdx.x * blockDim.x + threadIdx.x;
    if (i >= E + N) return;
    int s, d;
    if (i < E) { s = ei[i]; d = ei[E + i]; }
    else { s = d = i - E; }
    int p = offs[d] + atomicAdd(&cursor[d], 1);
    csr[p] = s;
}

__global__ void k_gstart(const int* __restrict__ batch, int N, int* gstart, int G) {
    int g = blockIdx.x * blockDim.x + threadIdx.x;
    if (g > G) return;
    int lo = 0, hi = N;
    while (lo < hi) {
        int mid = (lo + hi) >> 1;
        if (batch[mid] < g) lo = mid + 1; else hi = mid;
    }
    gstart[g] = lo;
}

// ---------- pre-scaled cast: g0 = fp16(dis * x) ----------
__global__ __launch_bounds__(256) void k_cast(
    const float* __restrict__ x, const float* __restrict__ dis,
    __half* __restrict__ hx, int npairs)
{
    int i = blockIdx.x * blockDim.x + threadIdx.x;
    if (i >= npairs) return;
    float2 v = ((const float2*)x)[i];
    float d = dis[i >> 6];
    ((__half2*)hx)[i] = __floats2half2_rn(d * v.x, d * v.y);
}

// ---------- GCN aggregation: 16 lanes/node, 8 feats/lane; input pre-scaled ----------
__global__ __launch_bounds__(256) void k_gcn_agg(
    const __half* __restrict__ g, const int* __restrict__ csr,
    const int* __restrict__ offs, const float* __restrict__ dis,
    float* __restrict__ agg, int N)
{
    int node = (blockIdx.x * blockDim.x + threadIdx.x) >> 4;
    int l = threadIdx.x & 15;
    if (node >= N) return;
    int j0 = offs[node], j1 = offs[node + 1];
    float dd = dis[node];
    const uint4* hp = (const uint4*)g + l;   // row stride: 16 uint4
    float acc[8] = {0.f, 0.f, 0.f, 0.f, 0.f, 0.f, 0.f, 0.f};
    int j = j0;
    for (; j + 4 <= j1; j += 4) {
        int s0 = csr[j + 0], s1 = csr[j + 1], s2 = csr[j + 2], s3 = csr[j + 3];
        uint4 u0 = hp[(size_t)s0 * 16];
        uint4 u1 = hp[(size_t)s1 * 16];
        uint4 u2 = hp[(size_t)s2 * 16];
        uint4 u3 = hp[(size_t)s3 * 16];
        float f0[8], f1[8], f2[8], f3[8];
        unpack8(u0, f0); unpack8(u1, f1); unpack8(u2, f2); unpack8(u3, f3);
#pragma unroll
        for (int i = 0; i < 8; ++i)
            acc[i] += f0[i] + f1[i] + f2[i] + f3[i];
    }
    for (; j < j1; ++j) {
        int s = csr[j];
        uint4 u = hp[(size_t)s * 16];
        float f[8]; unpack8(u, f);
#pragma unroll
        for (int i = 0; i < 8; ++i) acc[i] += f[i];
    }
    float* op = agg + (size_t)node * 128 + l * 8;
    *(float4*)op       = make_float4(dd * acc[0], dd * acc[1], dd * acc[2], dd * acc[3]);
    *(float4*)(op + 4) = make_float4(dd * acc[4], dd * acc[5], dd * acc[6], dd * acc[7]);
}

// ---------- fused GEMM: out(fp16) = [scale*] tanh(in @ W + b); 64-row tile, 8x4/thread ----
__global__ __launch_bounds__(256) void k_gemm_bias_tanh(
    const float* __restrict__ in, const float* __restrict__ W,
    const float* __restrict__ bias, const float* __restrict__ scale,
    __half* __restrict__ out, int nrows, float* __restrict__ invn_out)
{
    __shared__ float Wl[64][128];    // 32 KB (half of K)
    __shared__ float inT[128][72];   // k-major input tile, 64 rows + pad, 36.9 KB
    int tid = threadIdx.x;
    int row0 = blockIdx.x * 64;

    // stage input tile transposed: inT[k][r]
    for (int t = tid; t < 2048; t += 256) {
        int r = t >> 5, k4 = t & 31;
        int row = row0 + r;
        float4 v = make_float4(0.f, 0.f, 0.f, 0.f);
        if (row < nrows) v = *(const float4*)(in + (size_t)row * 128 + k4 * 4);
        inT[k4 * 4 + 0][r] = v.x;
        inT[k4 * 4 + 1][r] = v.y;
        inT[k4 * 4 + 2][r] = v.z;
        inT[k4 * 4 + 3][r] = v.w;
    }

    int cg = tid & 31;   // col group: cols cg*4..+3
    int rg = tid >> 5;   // row group: rows rg*8..+7
    float acc[8][4] = {};

    for (int kt = 0; kt < 2; ++kt) {
        __syncthreads();
        for (int t = tid; t < 2048; t += 256) {
            int k = t >> 5, c4 = t & 31;
            *(float4*)&Wl[k][c4 * 4] =
                *(const float4*)(W + (size_t)(kt * 64 + k) * 128 + c4 * 4);
        }
        __syncthreads();
#pragma unroll 4
        for (int k = 0; k < 64; ++k) {
            float4 a0 = *(const float4*)&inT[kt * 64 + k][rg * 8];
            float4 a1 = *(const float4*)&inT[kt * 64 + k][rg * 8 + 4];
            float4 wv = *(const float4*)&Wl[k][cg * 4];
            float av[8] = {a0.x, a0.y, a0.z, a0.w, a1.x, a1.y, a1.z, a1.w};
            float wvv[4] = {wv.x, wv.y, wv.z, wv.w};
#pragma unroll
            for (int i = 0; i < 8; ++i)
#pragma unroll
                for (int j = 0; j < 4; ++j)
                    acc[i][j] += av[i] * wvv[j];
        }
    }

    float4 bb = *(const float4*)(bias + cg * 4);
    float bv[4] = {bb.x, bb.y, bb.z, bb.w};
    float sq[8];
#pragma unroll
    for (int i = 0; i < 8; ++i) {
        int row = row0 + rg * 8 + i;
        float ox = tanhf(acc[i][0] + bv[0]);
        float oy = tanhf(acc[i][1] + bv[1]);
        float oz = tanhf(acc[i][2] + bv[2]);
        float ow = tanhf(acc[i][3] + bv[3]);
        sq[i] = ox * ox + oy * oy + oz * oz + ow * ow;
        if (row < nrows) {
            float sc = scale ? scale[row] : 1.0f;
            union { __half2 h[2]; uint2 u; } pk;
            pk.h[0] = __floats2half2_rn(sc * ox, sc * oy);
            pk.h[1] = __floats2half2_rn(sc * oz, sc * ow);
            *(uint2*)(out + (size_t)row * 128 + cg * 4) = pk.u;
        }
    }
    if (invn_out) {
#pragma unroll
        for (int i = 0; i < 8; ++i) {
#pragma unroll
            for (int off = 16; off > 0; off >>= 1) sq[i] += __shfl_xor(sq[i], off, 64);
            int row = row0 + rg * 8 + i;
            if (cg == 0 && row < nrows)
                invn_out[row] = 1.0f / fmaxf(sqrtf(sq[i]), 1e-12f);
        }
    }
}

// ---------- AGNN layer: 16 lanes/node, shift-free softmax, fused tanh ----------
__global__ __launch_bounds__(256) void k_agnn(
    const __half* __restrict__ h, const int* __restrict__ csr,
    const int* __restrict__ offs, const float* __restrict__ invn,
    const float* __restrict__ beta_p, __half* __restrict__ out, int N,
    float* __restrict__ invn_out)
{
    int node = (blockIdx.x * blockDim.x + threadIdx.x) >> 4;
    int l = threadIdx.x & 15;
    if (node >= N) return;
    int j0 = offs[node], j1 = offs[node + 1];
    const uint4* hp = (const uint4*)h + l;
    float hd[8]; unpack8(hp[(size_t)node * 16], hd);
    float bi = beta_p[0] * invn[node];
    float denom = 0.f;
    float acc[8] = {0.f, 0.f, 0.f, 0.f, 0.f, 0.f, 0.f, 0.f};
    int j = j0;
    for (; j + 2 <= j1; j += 2) {
        int s0 = csr[j], s1 = csr[j + 1];
        float in0 = invn[s0], in1 = invn[s1];
        uint4 u0 = hp[(size_t)s0 * 16];
        uint4 u1 = hp[(size_t)s1 * 16];
        float f0[8], f1[8];
        unpack8(u0, f0); unpack8(u1, f1);
        float d0 = 0.f, d1 = 0.f;
#pragma unroll
        for (int i = 0; i < 8; ++i) { d0 += f0[i] * hd[i]; d1 += f1[i] * hd[i]; }
#pragma unroll
        for (int off = 1; off < 16; off <<= 1) {
            d0 += __shfl_xor(d0, off, 64);
            d1 += __shfl_xor(d1, off, 64);
        }
        float p0 = __expf(bi * in0 * d0);
        float p1 = __expf(bi * in1 * d1);
        denom += p0 + p1;
#pragma unroll
        for (int i = 0; i < 8; ++i) acc[i] += p0 * f0[i] + p1 * f1[i];
    }
    for (; j < j1; ++j) {
        int s = csr[j];
        float ins = invn[s];
        uint4 u = hp[(size_t)s * 16];
        float f[8]; unpack8(u, f);
        float d = 0.f;
#pragma unroll
        for (int i = 0; i < 8; ++i) d += f[i] * hd[i];
#pragma unroll
        for (int off = 1; off < 16; off <<= 1) d += __shfl_xor(d, off, 64);
        float p = __expf(bi * ins * d);
        denom += p;
#pragma unroll
        for (int i = 0; i < 8; ++i) acc[i] += p * f[i];
    }
    float inv = 1.0f / denom;
    float o[8];
#pragma unroll
    for (int i = 0; i < 8; ++i) o[i] = tanhf(acc[i] * inv);
    union { uint4 u; __half2 h2[4]; } P;
    P.h2[0] = __floats2half2_rn(o[0], o[1]);
    P.h2[1] = __floats2half2_rn(o[2], o[3]);
    P.h2[2] = __floats2half2_rn(o[4], o[5]);
    P.h2[3] = __floats2half2_rn(o[6], o[7]);
    ((uint4*)out)[(size_t)node * 16 + l] = P.u;
    if (invn_out) {
        float s2 = 0.f;
#pragma unroll
        for (int i = 0; i < 8; ++i) s2 += o[i] * o[i];
#pragma unroll
        for (int off = 1; off < 16; off <<= 1) s2 += __shfl_xor(s2, off, 64);
        if (l == 0) invn_out[node] = 1.0f / fmaxf(sqrtf(s2), 1e-12f);
    }
}

// ---------- per-graph mean pool + layernorm + final linear (16 lanes/graph) ----------
__global__ __launch_bounds__(256) void k_pool(
    const __half* __restrict__ h, const int* __restrict__ gstart,
    const float* __restrict__ Wl, const float* __restrict__ bl,
    float* __restrict__ out, int G)
{
    int g = (blockIdx.x * blockDim.x + threadIdx.x) >> 4;
    int l = threadIdx.x & 15;
    if (g >= G) return;
    int s = gstart[g], e = gstart[g + 1];
    const uint4* hp = (const uint4*)h + l;
    float acc[8] = {0.f, 0.f, 0.f, 0.f, 0.f, 0.f, 0.f, 0.f};
    for (int n = s; n < e; ++n) {
        float f[8]; unpack8(hp[(size_t)n * 16], f);
#pragma unroll
        for (int i = 0; i < 8; ++i) acc[i] += f[i];
    }
    float inv = 1.0f / fmaxf((float)(e - s), 1.0f);
#pragma unroll
    for (int i = 0; i < 8; ++i) acc[i] *= inv;
    float part = 0.f;
#pragma unroll
    for (int i = 0; i < 8; ++i) part += acc[i];
#pragma unroll
    for (int off = 1; off < 16; off <<= 1) part += __shfl_xor(part, off, 64);
    float mu = part * (1.0f / 128.0f);
    float vpart = 0.f;
#pragma unroll
    for (int i = 0; i < 8; ++i) { float d = acc[i] - mu; vpart += d * d; }
#pragma unroll
    for (int off = 1; off < 16; off <<= 1) vpart += __shfl_xor(vpart, off, 64);
    float r = rsqrtf(vpart * (1.0f / 128.0f) + 1e-5f);
    float4 w0 = *(const float4*)(Wl + l * 8);
    float4 w1 = *(const float4*)(Wl + l * 8 + 4);
    float wv[8] = {w0.x, w0.y, w0.z, w0.w, w1.x, w1.y, w1.z, w1.w};
    float dot = 0.f;
#pragma unroll
    for (int i = 0; i < 8; ++i) dot += (acc[i] - mu) * r * wv[i];
#pragma unroll
    for (int off = 1; off < 16; off <<= 1) dot += __shfl_xor(dot, off, 64);
    if (l == 0) out[g] = dot + bl[0];
}

extern "C" void kernel_launch(void* const* d_in, const int* in_sizes, int n_in,
                              void* d_out, int out_size, void* d_ws, size_t ws_size,
                              hipStream_t stream) {
    const float* x  = (const float*)d_in[0];
    const int* ei   = (const int*)d_in[1];      // [2][E]
    const int* batch = (const int*)d_in[2];
    const float* Ws[5] = {(const float*)d_in[3], (const float*)d_in[5],
                          (const float*)d_in[7], (const float*)d_in[9],
                          (const float*)d_in[11]};
    const float* bs[5] = {(const float*)d_in[4], (const float*)d_in[6],
                          (const float*)d_in[8], (const float*)d_in[10],
                          (const float*)d_in[12]};
    const float* beta1 = (const float*)d_in[13];
    const float* beta2 = (const float*)d_in[14];
    const float* Wl = (const float*)d_in[15];
    const float* bl = (const float*)d_in[16];
    float* out = (float*)d_out;

    int N = in_sizes[0] / 128;
    int E = in_sizes[1] / 2;
    int G = out_size;

    char* ws = (char*)d_ws;
    size_t off = 0;
    auto alloc = [&](size_t bytes) -> void* {
        void* p = ws + off;
        off = (off + bytes + 255) & ~(size_t)255;
        return p;
    };
    float*  agg  = (float*)alloc((size_t)N * 128 * 4);
    __half* hA   = (__half*)alloc((size_t)N * 128 * 2);
    __half* hB   = (__half*)alloc((size_t)N * 128 * 2);
    int*   deg   = (int*)alloc((size_t)N * 4);
    int*   offs  = (int*)alloc((size_t)(N + 1) * 4);
    int*   cursor= (int*)alloc((size_t)N * 4);
    int*   csr   = (int*)alloc((size_t)(E + N) * 4);
    float* dis   = (float*)alloc((size_t)N * 4);
    float* invn  = (float*)alloc((size_t)N * 4);
    float* invn2 = (float*)alloc((size_t)N * 4);
    int nb = (N + 1023) / 1024;
    int*   part  = (int*)alloc((size_t)nb * 4);
    int*   gst   = (int*)alloc((size_t)(G + 1) * 4);

    // CSR build + pre-scaled x cast
    k_init_deg<<<(N + 255) / 256, 256, 0, stream>>>(deg, N);
    k_count<<<(E + 255) / 256, 256, 0, stream>>>(ei + E, deg, E);
    k_dis<<<(N + 255) / 256, 256, 0, stream>>>(deg, dis, N);
    k_scan1<<<nb, 256, 0, stream>>>(deg, part, N);
    k_scan2<<<1, 64, 0, stream>>>(part, nb, offs, N);
    k_scan3<<<nb, 256, 0, stream>>>(deg, part, offs, N);
    hipMemsetAsync(cursor, 0, (size_t)N * 4, stream);
    k_fill<<<(E + N + 255) / 256, 256, 0, stream>>>(ei, E, N, offs, cursor, csr);
    k_gstart<<<(G + 1 + 255) / 256, 256, 0, stream>>>(batch, N, gst, G);
    k_cast<<<(N * 64 + 255) / 256, 256, 0, stream>>>(x, dis, hA, N * 64);

    int aggBlocks = (N + 15) / 16;   // 16 nodes per 256-thread block
    int gemmBlocks = (N + 63) / 64;

    // 5 GCN layers; layers 0-3 write dis-scaled fp16; layer 4 writes unscaled + invn
    const __half* hin = hA;
    __half* hout = hB;
    for (int l = 0; l < 5; ++l) {
        k_gcn_agg<<<aggBlocks, 256, 0, stream>>>(hin, csr, offs, dis, agg, N);
        k_gemm_bias_tanh<<<gemmBlocks, 256, 0, stream>>>(
            agg, Ws[l], bs[l], (l < 4) ? dis : nullptr, hout, N,
            (l == 4) ? invn : nullptr);
        const __half* t = hin; hin = hout; hout = (__half*)t;
    }
    // after loop: hin = h5 (hB), hout = hA
    k_agnn<<<aggBlocks, 256, 0, stream>>>(hin, csr, offs, invn, beta1, hout, N, invn2);
    k_agnn<<<aggBlocks, 256, 0, stream>>>(hout, csr, offs, invn2, beta2, (__half*)hin, N, nullptr);
    k_pool<<<(G + 15) / 16, 256, 0, stream>>>(hin, gst, Wl, bl, out, G);
}

// Round 6
// 1010.081 us; speedup vs baseline: 1.1039x; 1.1039x over previous
//
#include <hip/hip_runtime.h>
#include <hip/hip_fp16.h>
#include <math.h>

__device__ __forceinline__ void unpack8(uint4 u, float* f) {
    union { uint4 u; __half2 h2[4]; } U; U.u = u;
    float2 a = __half22float2(U.h2[0]);
    float2 b = __half22float2(U.h2[1]);
    float2 c = __half22float2(U.h2[2]);
    float2 d = __half22float2(U.h2[3]);
    f[0] = a.x; f[1] = a.y; f[2] = b.x; f[3] = b.y;
    f[4] = c.x; f[5] = c.y; f[6] = d.x; f[7] = d.y;
}

// ---------- preprocessing ----------
__global__ void k_init_deg(int* deg, int N) {
    int i = blockIdx.x * blockDim.x + threadIdx.x;
    if (i < N) deg[i] = 1;  // self loop
}

__global__ void k_count(const int* __restrict__ dst, int* deg, int E) {
    int i = blockIdx.x * blockDim.x + threadIdx.x;
    if (i < E) atomicAdd(&deg[dst[i]], 1);
}

__global__ void k_dis(const int* __restrict__ deg, float* dis, int N) {
    int i = blockIdx.x * blockDim.x + threadIdx.x;
    if (i < N) dis[i] = rsqrtf((float)deg[i]);  // deg >= 1 always
}

// exclusive scan of deg[0..N) -> offs[0..N], offs[N] = total
__global__ void k_scan1(const int* __restrict__ deg, int* part, int N) {
    int base = blockIdx.x * 1024;
    int tid = threadIdx.x;
    int s = 0;
#pragma unroll
    for (int j = 0; j < 4; ++j) {
        int idx = base + tid * 4 + j;
        if (idx < N) s += deg[idx];
    }
    __shared__ int sm[256];
    sm[tid] = s;
    __syncthreads();
    for (int off = 128; off > 0; off >>= 1) {
        if (tid < off) sm[tid] += sm[tid + off];
        __syncthreads();
    }
    if (tid == 0) part[blockIdx.x] = sm[0];
}

__global__ void k_scan2(int* part, int nb, int* offs, int N) {
    if (blockIdx.x == 0 && threadIdx.x == 0) {
        int run = 0;
        for (int b = 0; b < nb; ++b) { int t = part[b]; part[b] = run; run += t; }
        offs[N] = run;
    }
}

__global__ void k_scan3(const int* __restrict__ deg, const int* __restrict__ part,
                        int* offs, int N) {
    __shared__ int sm[256];
    int base = blockIdx.x * 1024;
    int tid = threadIdx.x;
    int a[4];
    int s = 0;
#pragma unroll
    for (int j = 0; j < 4; ++j) {
        int idx = base + tid * 4 + j;
        a[j] = (idx < N) ? deg[idx] : 0;
        s += a[j];
    }
    sm[tid] = s;
    __syncthreads();
    for (int off = 1; off < 256; off <<= 1) {
        int v = (tid >= off) ? sm[tid - off] : 0;
        __syncthreads();
        sm[tid] += v;
        __syncthreads();
    }
    int excl = sm[tid] - s + part[blockIdx.x];
#pragma unroll
    for (int j = 0; j < 4; ++j) {
        int idx = base + tid * 4 + j;
        if (idx < N) offs[idx] = excl;
        excl += a[j];
    }
}

__global__ void k_fill(const int* __restrict__ ei, int E, int N,
                       const int* __restrict__ offs, int* cursor, int* csr) {
    int i = blockIdx.x * blockDim.x + threadIdx.x;
    if (i >= E + N) return;
    int s, d;
    if (i < E) { s = ei[i]; d = ei[E + i]; }
    else { s = d = i - E; }
    int p = offs[d] + atomicAdd(&cursor[d], 1);
    csr[p] = s;
}

__global__ void k_gstart(const int* __restrict__ batch, int N, int* gstart, int G) {
    int g = blockIdx.x * blockDim.x + threadIdx.x;
    if (g > G) return;
    int lo = 0, hi = N;
    while (lo < hi) {
        int mid = (lo + hi) >> 1;
        if (batch[mid] < g) lo = mid + 1; else hi = mid;
    }
    gstart[g] = lo;
}

// ---------- pre-scaled cast: g0 = fp16(dis * x) ----------
__global__ __launch_bounds__(256) void k_cast(
    const float* __restrict__ x, const float* __restrict__ dis,
    __half* __restrict__ hx, int npairs)
{
    int i = blockIdx.x * blockDim.x + threadIdx.x;
    if (i >= npairs) return;
    float2 v = ((const float2*)x)[i];
    float d = dis[i >> 6];
    ((__half2*)hx)[i] = __floats2half2_rn(d * v.x, d * v.y);
}

// ---------- GCN aggregation: 16 lanes/node, 8 feats/lane; fp16 in/out ----------
__global__ __launch_bounds__(256) void k_gcn_agg(
    const __half* __restrict__ g, const int* __restrict__ csr,
    const int* __restrict__ offs, const float* __restrict__ dis,
    __half* __restrict__ agg, int N)
{
    int node = (blockIdx.x * blockDim.x + threadIdx.x) >> 4;
    int l = threadIdx.x & 15;
    if (node >= N) return;
    int j0 = offs[node], j1 = offs[node + 1];
    float dd = dis[node];
    const uint4* hp = (const uint4*)g + l;   // row stride: 16 uint4
    float acc[8] = {0.f, 0.f, 0.f, 0.f, 0.f, 0.f, 0.f, 0.f};
    int j = j0;
    for (; j + 4 <= j1; j += 4) {
        int s0 = csr[j + 0], s1 = csr[j + 1], s2 = csr[j + 2], s3 = csr[j + 3];
        uint4 u0 = hp[(size_t)s0 * 16];
        uint4 u1 = hp[(size_t)s1 * 16];
        uint4 u2 = hp[(size_t)s2 * 16];
        uint4 u3 = hp[(size_t)s3 * 16];
        float f0[8], f1[8], f2[8], f3[8];
        unpack8(u0, f0); unpack8(u1, f1); unpack8(u2, f2); unpack8(u3, f3);
#pragma unroll
        for (int i = 0; i < 8; ++i)
            acc[i] += f0[i] + f1[i] + f2[i] + f3[i];
    }
    for (; j < j1; ++j) {
        int s = csr[j];
        uint4 u = hp[(size_t)s * 16];
        float f[8]; unpack8(u, f);
#pragma unroll
        for (int i = 0; i < 8; ++i) acc[i] += f[i];
    }
    union { uint4 u; __half2 h2[4]; } P;
    P.h2[0] = __floats2half2_rn(dd * acc[0], dd * acc[1]);
    P.h2[1] = __floats2half2_rn(dd * acc[2], dd * acc[3]);
    P.h2[2] = __floats2half2_rn(dd * acc[4], dd * acc[5]);
    P.h2[3] = __floats2half2_rn(dd * acc[6], dd * acc[7]);
    ((uint4*)agg)[(size_t)node * 16 + l] = P.u;
}

// ---------- fused GEMM (R4 structure): out(fp16) = [scale*] tanh(in @ W + b) ----------
// in: fp16 nrows x 128, 32-row tile, 4x4 microtile, 50 KB LDS (3 blocks/CU)
__global__ __launch_bounds__(256) void k_gemm_bias_tanh(
    const __half* __restrict__ in, const float* __restrict__ W,
    const float* __restrict__ bias, const float* __restrict__ scale,
    __half* __restrict__ out, int nrows, float* __restrict__ invn_out)
{
    __shared__ float Wl[64][128];    // 32 KB (half of K)
    __shared__ float inT[128][36];   // transposed input tile, stride 36 keeps 16B align
    int tid = threadIdx.x;
    int row0 = blockIdx.x * 32;

    // stage input tile transposed: inT[k][r]; fp16 source, 8 halves per chunk
    for (int t = tid; t < 512; t += 256) {
        int r = t >> 4, k8 = t & 15;
        int row = row0 + r;
        uint4 u = make_uint4(0u, 0u, 0u, 0u);
        if (row < nrows) u = *(const uint4*)(in + (size_t)row * 128 + k8 * 8);
        float f[8]; unpack8(u, f);
#pragma unroll
        for (int q = 0; q < 8; ++q) inT[k8 * 8 + q][r] = f[q];
    }

    int cg = tid & 31;   // col group: cols cg*4..+3
    int rg = tid >> 5;   // row group: rows rg*4..+3
    float acc[4][4] = {};

    for (int kt = 0; kt < 2; ++kt) {
        __syncthreads();
        for (int t = tid; t < 2048; t += 256) {
            int k = t >> 5, c4 = t & 31;
            *(float4*)&Wl[k][c4 * 4] =
                *(const float4*)(W + (size_t)(kt * 64 + k) * 128 + c4 * 4);
        }
        __syncthreads();
#pragma unroll 4
        for (int k = 0; k < 64; ++k) {
            float4 a = *(const float4*)&inT[kt * 64 + k][rg * 4];
            float4 wv = *(const float4*)&Wl[k][cg * 4];
            float av[4] = {a.x, a.y, a.z, a.w};
            float wvv[4] = {wv.x, wv.y, wv.z, wv.w};
#pragma unroll
            for (int i = 0; i < 4; ++i)
#pragma unroll
                for (int j = 0; j < 4; ++j)
                    acc[i][j] += av[i] * wvv[j];
        }
    }

    float4 bb = *(const float4*)(bias + cg * 4);
    float bv[4] = {bb.x, bb.y, bb.z, bb.w};
    float sq[4];
#pragma unroll
    for (int i = 0; i < 4; ++i) {
        int row = row0 + rg * 4 + i;
        float ox = tanhf(acc[i][0] + bv[0]);
        float oy = tanhf(acc[i][1] + bv[1]);
        float oz = tanhf(acc[i][2] + bv[2]);
        float ow = tanhf(acc[i][3] + bv[3]);
        sq[i] = ox * ox + oy * oy + oz * oz + ow * ow;
        if (row < nrows) {
            float sc = scale ? scale[row] : 1.0f;
            union { __half2 h[2]; uint2 u; } pk;
            pk.h[0] = __floats2half2_rn(sc * ox, sc * oy);
            pk.h[1] = __floats2half2_rn(sc * oz, sc * ow);
            *(uint2*)(out + (size_t)row * 128 + cg * 4) = pk.u;
        }
    }
    if (invn_out) {
#pragma unroll
        for (int i = 0; i < 4; ++i) {
#pragma unroll
            for (int off = 16; off > 0; off >>= 1) sq[i] += __shfl_xor(sq[i], off, 64);
            int row = row0 + rg * 4 + i;
            if (cg == 0 && row < nrows)
                invn_out[row] = 1.0f / fmaxf(sqrtf(sq[i]), 1e-12f);
        }
    }
}

// ---------- AGNN layer: 16 lanes/node, shift-free softmax, fused tanh ----------
__global__ __launch_bounds__(256) void k_agnn(
    const __half* __restrict__ h, const int* __restrict__ csr,
    const int* __restrict__ offs, const float* __restrict__ invn,
    const float* __restrict__ beta_p, __half* __restrict__ out, int N,
    float* __restrict__ invn_out)
{
    int node = (blockIdx.x * blockDim.x + threadIdx.x) >> 4;
    int l = threadIdx.x & 15;
    if (node >= N) return;
    int j0 = offs[node], j1 = offs[node + 1];
    const uint4* hp = (const uint4*)h + l;
    float hd[8]; unpack8(hp[(size_t)node * 16], hd);
    float bi = beta_p[0] * invn[node];
    float denom = 0.f;
    float acc[8] = {0.f, 0.f, 0.f, 0.f, 0.f, 0.f, 0.f, 0.f};
    int j = j0;
    for (; j + 2 <= j1; j += 2) {
        int s0 = csr[j], s1 = csr[j + 1];
        float in0 = invn[s0], in1 = invn[s1];
        uint4 u0 = hp[(size_t)s0 * 16];
        uint4 u1 = hp[(size_t)s1 * 16];
        float f0[8], f1[8];
        unpack8(u0, f0); unpack8(u1, f1);
        float d0 = 0.f, d1 = 0.f;
#pragma unroll
        for (int i = 0; i < 8; ++i) { d0 += f0[i] * hd[i]; d1 += f1[i] * hd[i]; }
#pragma unroll
        for (int off = 1; off < 16; off <<= 1) {
            d0 += __shfl_xor(d0, off, 64);
            d1 += __shfl_xor(d1, off, 64);
        }
        float p0 = __expf(bi * in0 * d0);
        float p1 = __expf(bi * in1 * d1);
        denom += p0 + p1;
#pragma unroll
        for (int i = 0; i < 8; ++i) acc[i] += p0 * f0[i] + p1 * f1[i];
    }
    for (; j < j1; ++j) {
        int s = csr[j];
        float ins = invn[s];
        uint4 u = hp[(size_t)s * 16];
        float f[8]; unpack8(u, f);
        float d = 0.f;
#pragma unroll
        for (int i = 0; i < 8; ++i) d += f[i] * hd[i];
#pragma unroll
        for (int off = 1; off < 16; off <<= 1) d += __shfl_xor(d, off, 64);
        float p = __expf(bi * ins * d);
        denom += p;
#pragma unroll
        for (int i = 0; i < 8; ++i) acc[i] += p * f[i];
    }
    float inv = 1.0f / denom;
    float o[8];
#pragma unroll
    for (int i = 0; i < 8; ++i) o[i] = tanhf(acc[i] * inv);
    union { uint4 u; __half2 h2[4]; } P;
    P.h2[0] = __floats2half2_rn(o[0], o[1]);
    P.h2[1] = __floats2half2_rn(o[2], o[3]);
    P.h2[2] = __floats2half2_rn(o[4], o[5]);
    P.h2[3] = __floats2half2_rn(o[6], o[7]);
    ((uint4*)out)[(size_t)node * 16 + l] = P.u;
    if (invn_out) {
        float s2 = 0.f;
#pragma unroll
        for (int i = 0; i < 8; ++i) s2 += o[i] * o[i];
#pragma unroll
        for (int off = 1; off < 16; off <<= 1) s2 += __shfl_xor(s2, off, 64);
        if (l == 0) invn_out[node] = 1.0f / fmaxf(sqrtf(s2), 1e-12f);
    }
}

// ---------- per-graph mean pool + layernorm + final linear (16 lanes/graph) ----------
__global__ __launch_bounds__(256) void k_pool(
    const __half* __restrict__ h, const int* __restrict__ gstart,
    const float* __restrict__ Wl, const float* __restrict__ bl,
    float* __restrict__ out, int G)
{
    int g = (blockIdx.x * blockDim.x + threadIdx.x) >> 4;
    int l = threadIdx.x & 15;
    if (g >= G) return;
    int s = gstart[g], e = gstart[g + 1];
    const uint4* hp = (const uint4*)h + l;
    float acc[8] = {0.f, 0.f, 0.f, 0.f, 0.f, 0.f, 0.f, 0.f};
    for (int n = s; n < e; ++n) {
        float f[8]; unpack8(hp[(size_t)n * 16], f);
#pragma unroll
        for (int i = 0; i < 8; ++i) acc[i] += f[i];
    }
    float inv = 1.0f / fmaxf((float)(e - s), 1.0f);
#pragma unroll
    for (int i = 0; i < 8; ++i) acc[i] *= inv;
    float part = 0.f;
#pragma unroll
    for (int i = 0; i < 8; ++i) part += acc[i];
#pragma unroll
    for (int off = 1; off < 16; off <<= 1) part += __shfl_xor(part, off, 64);
    float mu = part * (1.0f / 128.0f);
    float vpart = 0.f;
#pragma unroll
    for (int i = 0; i < 8; ++i) { float d = acc[i] - mu; vpart += d * d; }
#pragma unroll
    for (int off = 1; off < 16; off <<= 1) vpart += __shfl_xor(vpart, off, 64);
    float r = rsqrtf(vpart * (1.0f / 128.0f) + 1e-5f);
    float4 w0 = *(const float4*)(Wl + l * 8);
    float4 w1 = *(const float4*)(Wl + l * 8 + 4);
    float wv[8] = {w0.x, w0.y, w0.z, w0.w, w1.x, w1.y, w1.z, w1.w};
    float dot = 0.f;
#pragma unroll
    for (int i = 0; i < 8; ++i) dot += (acc[i] - mu) * r * wv[i];
#pragma unroll
    for (int off = 1; off < 16; off <<= 1) dot += __shfl_xor(dot, off, 64);
    if (l == 0) out[g] = dot + bl[0];
}

extern "C" void kernel_launch(void* const* d_in, const int* in_sizes, int n_in,
                              void* d_out, int out_size, void* d_ws, size_t ws_size,
                              hipStream_t stream) {
    const float* x  = (const float*)d_in[0];
    const int* ei   = (const int*)d_in[1];      // [2][E]
    const int* batch = (const int*)d_in[2];
    const float* Ws[5] = {(const float*)d_in[3], (const float*)d_in[5],
                          (const float*)d_in[7], (const float*)d_in[9],
                          (const float*)d_in[11]};
    const float* bs[5] = {(const float*)d_in[4], (const float*)d_in[6],
                          (const float*)d_in[8], (const float*)d_in[10],
                          (const float*)d_in[12]};
    const float* beta1 = (const float*)d_in[13];
    const float* beta2 = (const float*)d_in[14];
    const float* Wl = (const float*)d_in[15];
    const float* bl = (const float*)d_in[16];
    float* out = (float*)d_out;

    int N = in_sizes[0] / 128;
    int E = in_sizes[1] / 2;
    int G = out_size;

    char* ws = (char*)d_ws;
    size_t off = 0;
    auto alloc = [&](size_t bytes) -> void* {
        void* p = ws + off;
        off = (off + bytes + 255) & ~(size_t)255;
        return p;
    };
    __half* aggh = (__half*)alloc((size_t)N * 128 * 2);
    __half* hA   = (__half*)alloc((size_t)N * 128 * 2);
    __half* hB   = (__half*)alloc((size_t)N * 128 * 2);
    int*   deg   = (int*)alloc((size_t)N * 4);
    int*   offs  = (int*)alloc((size_t)(N + 1) * 4);
    int*   cursor= (int*)alloc((size_t)N * 4);
    int*   csr   = (int*)alloc((size_t)(E + N) * 4);
    float* dis   = (float*)alloc((size_t)N * 4);
    float* invn  = (float*)alloc((size_t)N * 4);
    float* invn2 = (float*)alloc((size_t)N * 4);
    int nb = (N + 1023) / 1024;
    int*   part  = (int*)alloc((size_t)nb * 4);
    int*   gst   = (int*)alloc((size_t)(G + 1) * 4);

    // CSR build + pre-scaled x cast
    k_init_deg<<<(N + 255) / 256, 256, 0, stream>>>(deg, N);
    k_count<<<(E + 255) / 256, 256, 0, stream>>>(ei + E, deg, E);
    k_dis<<<(N + 255) / 256, 256, 0, stream>>>(deg, dis, N);
    k_scan1<<<nb, 256, 0, stream>>>(deg, part, N);
    k_scan2<<<1, 64, 0, stream>>>(part, nb, offs, N);
    k_scan3<<<nb, 256, 0, stream>>>(deg, part, offs, N);
    hipMemsetAsync(cursor, 0, (size_t)N * 4, stream);
    k_fill<<<(E + N + 255) / 256, 256, 0, stream>>>(ei, E, N, offs, cursor, csr);
    k_gstart<<<(G + 1 + 255) / 256, 256, 0, stream>>>(batch, N, gst, G);
    k_cast<<<(N * 64 + 255) / 256, 256, 0, stream>>>(x, dis, hA, N * 64);

    int aggBlocks = (N + 15) / 16;   // 16 nodes per 256-thread block
    int gemmBlocks = (N + 31) / 32;

    // 5 GCN layers; layers 0-3 write dis-scaled fp16; layer 4 writes unscaled + invn
    const __half* hin = hA;
    __half* hout = hB;
    for (int l = 0; l < 5; ++l) {
        k_gcn_agg<<<aggBlocks, 256, 0, stream>>>(hin, csr, offs, dis, aggh, N);
        k_gemm_bias_tanh<<<gemmBlocks, 256, 0, stream>>>(
            aggh, Ws[l], bs[l], (l < 4) ? dis : nullptr, hout, N,
            (l == 4) ? invn : nullptr);
        const __half* t = hin; hin = hout; hout = (__half*)t;
    }
    // after loop: hin = h5 (hB), hout = hA
    k_agnn<<<aggBlocks, 256, 0, stream>>>(hin, csr, offs, invn, beta1, hout, N, invn2);
    k_agnn<<<aggBlocks, 256, 0, stream>>>(hout, csr, offs, invn2, beta2, (__half*)hin, N, nullptr);
    k_pool<<<(G + 15) / 16, 256, 0, stream>>>(hin, gst, Wl, bl, out, G);
}

// Round 7
// 931.146 us; speedup vs baseline: 1.1975x; 1.0848x over previous
//
#include <hip/hip_runtime.h>
#include <hip/hip_fp16.h>
#include <math.h>

__device__ __forceinline__ void unpack8(uint4 u, float* f) {
    union { uint4 u; __half2 h2[4]; } U; U.u = u;
    float2 a = __half22float2(U.h2[0]);
    float2 b = __half22float2(U.h2[1]);
    float2 c = __half22float2(U.h2[2]);
    float2 d = __half22float2(U.h2[3]);
    f[0] = a.x; f[1] = a.y; f[2] = b.x; f[3] = b.y;
    f[4] = c.x; f[5] = c.y; f[6] = d.x; f[7] = d.y;
}

// ---------- preprocessing ----------
__global__ void k_zero_deg(int* deg, int N) {
    int i = blockIdx.x * blockDim.x + threadIdx.x;
    if (i < N) deg[i] = 0;
}

// count real edges per dst; rank[i] = this edge's 0-based slot among same-dst edges
__global__ void k_count(const int* __restrict__ dst, int* deg, int* rank, int E) {
    int i = blockIdx.x * blockDim.x + threadIdx.x;
    if (i < E) rank[i] = atomicAdd(&deg[dst[i]], 1);
}

__global__ void k_dis(const int* __restrict__ deg, float* dis, int N) {
    int i = blockIdx.x * blockDim.x + threadIdx.x;
    if (i < N) dis[i] = rsqrtf((float)(deg[i] + 1));  // +1 self loop
}

// exclusive scan of (deg[i]+1) -> offs[0..N], offs[N] = total
__global__ void k_scan1(const int* __restrict__ deg, int* part, int N) {
    int base = blockIdx.x * 1024;
    int tid = threadIdx.x;
    int s = 0;
#pragma unroll
    for (int j = 0; j < 4; ++j) {
        int idx = base + tid * 4 + j;
        if (idx < N) s += deg[idx] + 1;
    }
    __shared__ int sm[256];
    sm[tid] = s;
    __syncthreads();
    for (int off = 128; off > 0; off >>= 1) {
        if (tid < off) sm[tid] += sm[tid + off];
        __syncthreads();
    }
    if (tid == 0) part[blockIdx.x] = sm[0];
}

__global__ void k_scan2(int* part, int nb, int* offs, int N) {
    if (blockIdx.x == 0 && threadIdx.x == 0) {
        int run = 0;
        for (int b = 0; b < nb; ++b) { int t = part[b]; part[b] = run; run += t; }
        offs[N] = run;
    }
}

__global__ void k_scan3(const int* __restrict__ deg, const int* __restrict__ part,
                        int* offs, int N) {
    __shared__ int sm[256];
    int base = blockIdx.x * 1024;
    int tid = threadIdx.x;
    int a[4];
    int s = 0;
#pragma unroll
    for (int j = 0; j < 4; ++j) {
        int idx = base + tid * 4 + j;
        a[j] = (idx < N) ? (deg[idx] + 1) : 0;
        s += a[j];
    }
    sm[tid] = s;
    __syncthreads();
    for (int off = 1; off < 256; off <<= 1) {
        int v = (tid >= off) ? sm[tid - off] : 0;
        __syncthreads();
        sm[tid] += v;
        __syncthreads();
    }
    int excl = sm[tid] - s + part[blockIdx.x];
#pragma unroll
    for (int j = 0; j < 4; ++j) {
        int idx = base + tid * 4 + j;
        if (idx < N) offs[idx] = excl;
        excl += a[j];
    }
}

// atomic-free fill: edge i -> csr[offs[d] + rank[i]]
__global__ void k_fill_edges(const int* __restrict__ ei, int E,
                             const int* __restrict__ offs,
                             const int* __restrict__ rank, int* csr) {
    int i = blockIdx.x * blockDim.x + threadIdx.x;
    if (i >= E) return;
    int s = ei[i], d = ei[E + i];
    csr[offs[d] + rank[i]] = s;
}

// self-loop of node n at last slot offs[n+1]-1
__global__ void k_fill_loops(const int* __restrict__ offs, int* csr, int N) {
    int n = blockIdx.x * blockDim.x + threadIdx.x;
    if (n < N) csr[offs[n + 1] - 1] = n;
}

__global__ void k_gstart(const int* __restrict__ batch, int N, int* gstart, int G) {
    int g = blockIdx.x * blockDim.x + threadIdx.x;
    if (g > G) return;
    int lo = 0, hi = N;
    while (lo < hi) {
        int mid = (lo + hi) >> 1;
        if (batch[mid] < g) lo = mid + 1; else hi = mid;
    }
    gstart[g] = lo;
}

// ---------- pre-scaled cast: g0 = fp16(dis * x) ----------
__global__ __launch_bounds__(256) void k_cast(
    const float* __restrict__ x, const float* __restrict__ dis,
    __half* __restrict__ hx, int npairs)
{
    int i = blockIdx.x * blockDim.x + threadIdx.x;
    if (i >= npairs) return;
    float2 v = ((const float2*)x)[i];
    float d = dis[i >> 6];
    ((__half2*)hx)[i] = __floats2half2_rn(d * v.x, d * v.y);
}

// ---------- GCN aggregation: 16 lanes/node, 8 feats/lane; fp16 in/out ----------
__global__ __launch_bounds__(256) void k_gcn_agg(
    const __half* __restrict__ g, const int* __restrict__ csr,
    const int* __restrict__ offs, const float* __restrict__ dis,
    __half* __restrict__ agg, int N)
{
    int node = (blockIdx.x * blockDim.x + threadIdx.x) >> 4;
    int l = threadIdx.x & 15;
    if (node >= N) return;
    int j0 = offs[node], j1 = offs[node + 1];
    float dd = dis[node];
    const uint4* hp = (const uint4*)g + l;   // row stride: 16 uint4
    float acc[8] = {0.f, 0.f, 0.f, 0.f, 0.f, 0.f, 0.f, 0.f};
    int j = j0;
    for (; j + 4 <= j1; j += 4) {
        int s0 = csr[j + 0], s1 = csr[j + 1], s2 = csr[j + 2], s3 = csr[j + 3];
        uint4 u0 = hp[(size_t)s0 * 16];
        uint4 u1 = hp[(size_t)s1 * 16];
        uint4 u2 = hp[(size_t)s2 * 16];
        uint4 u3 = hp[(size_t)s3 * 16];
        float f0[8], f1[8], f2[8], f3[8];
        unpack8(u0, f0); unpack8(u1, f1); unpack8(u2, f2); unpack8(u3, f3);
#pragma unroll
        for (int i = 0; i < 8; ++i)
            acc[i] += f0[i] + f1[i] + f2[i] + f3[i];
    }
    for (; j < j1; ++j) {
        int s = csr[j];
        uint4 u = hp[(size_t)s * 16];
        float f[8]; unpack8(u, f);
#pragma unroll
        for (int i = 0; i < 8; ++i) acc[i] += f[i];
    }
    union { uint4 u; __half2 h2[4]; } P;
    P.h2[0] = __floats2half2_rn(dd * acc[0], dd * acc[1]);
    P.h2[1] = __floats2half2_rn(dd * acc[2], dd * acc[3]);
    P.h2[2] = __floats2half2_rn(dd * acc[4], dd * acc[5]);
    P.h2[3] = __floats2half2_rn(dd * acc[6], dd * acc[7]);
    ((uint4*)agg)[(size_t)node * 16 + l] = P.u;
}

// ---------- fused GEMM: out(fp16) = [scale*] tanh(in @ W + b) ----------
// in: fp16 nrows x 128, 32-row tile, 4x4 microtile, 50 KB LDS (3 blocks/CU)
__global__ __launch_bounds__(256) void k_gemm_bias_tanh(
    const __half* __restrict__ in, const float* __restrict__ W,
    const float* __restrict__ bias, const float* __restrict__ scale,
    __half* __restrict__ out, int nrows, float* __restrict__ invn_out)
{
    __shared__ float Wl[64][128];    // 32 KB (half of K)
    __shared__ float inT[128][36];   // transposed input tile, stride 36 keeps 16B align
    int tid = threadIdx.x;
    int row0 = blockIdx.x * 32;

    // stage input tile transposed: inT[k][r]; fp16 source, 8 halves per chunk
    for (int t = tid; t < 512; t += 256) {
        int r = t >> 4, k8 = t & 15;
        int row = row0 + r;
        uint4 u = make_uint4(0u, 0u, 0u, 0u);
        if (row < nrows) u = *(const uint4*)(in + (size_t)row * 128 + k8 * 8);
        float f[8]; unpack8(u, f);
#pragma unroll
        for (int q = 0; q < 8; ++q) inT[k8 * 8 + q][r] = f[q];
    }

    int cg = tid & 31;   // col group: cols cg*4..+3
    int rg = tid >> 5;   // row group: rows rg*4..+3
    float acc[4][4] = {};

    for (int kt = 0; kt < 2; ++kt) {
        __syncthreads();
        for (int t = tid; t < 2048; t += 256) {
            int k = t >> 5, c4 = t & 31;
            *(float4*)&Wl[k][c4 * 4] =
                *(const float4*)(W + (size_t)(kt * 64 + k) * 128 + c4 * 4);
        }
        __syncthreads();
#pragma unroll 4
        for (int k = 0; k < 64; ++k) {
            float4 a = *(const float4*)&inT[kt * 64 + k][rg * 4];
            float4 wv = *(const float4*)&Wl[k][cg * 4];
            float av[4] = {a.x, a.y, a.z, a.w};
            float wvv[4] = {wv.x, wv.y, wv.z, wv.w};
#pragma unroll
            for (int i = 0; i < 4; ++i)
#pragma unroll
                for (int j = 0; j < 4; ++j)
                    acc[i][j] += av[i] * wvv[j];
        }
    }

    float4 bb = *(const float4*)(bias + cg * 4);
    float bv[4] = {bb.x, bb.y, bb.z, bb.w};
    float sq[4];
#pragma unroll
    for (int i = 0; i < 4; ++i) {
        int row = row0 + rg * 4 + i;
        float ox = tanhf(acc[i][0] + bv[0]);
        float oy = tanhf(acc[i][1] + bv[1]);
        float oz = tanhf(acc[i][2] + bv[2]);
        float ow = tanhf(acc[i][3] + bv[3]);
        sq[i] = ox * ox + oy * oy + oz * oz + ow * ow;
        if (row < nrows) {
            float sc = scale ? scale[row] : 1.0f;
            union { __half2 h[2]; uint2 u; } pk;
            pk.h[0] = __floats2half2_rn(sc * ox, sc * oy);
            pk.h[1] = __floats2half2_rn(sc * oz, sc * ow);
            *(uint2*)(out + (size_t)row * 128 + cg * 4) = pk.u;
        }
    }
    if (invn_out) {
#pragma unroll
        for (int i = 0; i < 4; ++i) {
#pragma unroll
            for (int off = 16; off > 0; off >>= 1) sq[i] += __shfl_xor(sq[i], off, 64);
            int row = row0 + rg * 4 + i;
            if (cg == 0 && row < nrows)
                invn_out[row] = 1.0f / fmaxf(sqrtf(sq[i]), 1e-12f);
        }
    }
}

// ---------- AGNN layer: 16 lanes/node, shift-free softmax, fused tanh ----------
__global__ __launch_bounds__(256) void k_agnn(
    const __half* __restrict__ h, const int* __restrict__ csr,
    const int* __restrict__ offs, const float* __restrict__ invn,
    const float* __restrict__ beta_p, __half* __restrict__ out, int N,
    float* __restrict__ invn_out)
{
    int node = (blockIdx.x * blockDim.x + threadIdx.x) >> 4;
    int l = threadIdx.x & 15;
    if (node >= N) return;
    int j0 = offs[node], j1 = offs[node + 1];
    const uint4* hp = (const uint4*)h + l;
    float hd[8]; unpack8(hp[(size_t)node * 16], hd);
    float bi = beta_p[0] * invn[node];
    float denom = 0.f;
    float acc[8] = {0.f, 0.f, 0.f, 0.f, 0.f, 0.f, 0.f, 0.f};
    int j = j0;
    for (; j + 2 <= j1; j += 2) {
        int s0 = csr[j], s1 = csr[j + 1];
        float in0 = invn[s0], in1 = invn[s1];
        uint4 u0 = hp[(size_t)s0 * 16];
        uint4 u1 = hp[(size_t)s1 * 16];
        float f0[8], f1[8];
        unpack8(u0, f0); unpack8(u1, f1);
        float d0 = 0.f, d1 = 0.f;
#pragma unroll
        for (int i = 0; i < 8; ++i) { d0 += f0[i] * hd[i]; d1 += f1[i] * hd[i]; }
#pragma unroll
        for (int off = 1; off < 16; off <<= 1) {
            d0 += __shfl_xor(d0, off, 64);
            d1 += __shfl_xor(d1, off, 64);
        }
        float p0 = __expf(bi * in0 * d0);
        float p1 = __expf(bi * in1 * d1);
        denom += p0 + p1;
#pragma unroll
        for (int i = 0; i < 8; ++i) acc[i] += p0 * f0[i] + p1 * f1[i];
    }
    for (; j < j1; ++j) {
        int s = csr[j];
        float ins = invn[s];
        uint4 u = hp[(size_t)s * 16];
        float f[8]; unpack8(u, f);
        float d = 0.f;
#pragma unroll
        for (int i = 0; i < 8; ++i) d += f[i] * hd[i];
#pragma unroll
        for (int off = 1; off < 16; off <<= 1) d += __shfl_xor(d, off, 64);
        float p = __expf(bi * ins * d);
        denom += p;
#pragma unroll
        for (int i = 0; i < 8; ++i) acc[i] += p * f[i];
    }
    float inv = 1.0f / denom;
    float o[8];
#pragma unroll
    for (int i = 0; i < 8; ++i) o[i] = tanhf(acc[i] * inv);
    union { uint4 u; __half2 h2[4]; } P;
    P.h2[0] = __floats2half2_rn(o[0], o[1]);
    P.h2[1] = __floats2half2_rn(o[2], o[3]);
    P.h2[2] = __floats2half2_rn(o[4], o[5]);
    P.h2[3] = __floats2half2_rn(o[6], o[7]);
    ((uint4*)out)[(size_t)node * 16 + l] = P.u;
    if (invn_out) {
        float s2 = 0.f;
#pragma unroll
        for (int i = 0; i < 8; ++i) s2 += o[i] * o[i];
#pragma unroll
        for (int off = 1; off < 16; off <<= 1) s2 += __shfl_xor(s2, off, 64);
        if (l == 0) invn_out[node] = 1.0f / fmaxf(sqrtf(s2), 1e-12f);
    }
}

// ---------- per-graph mean pool + layernorm + final linear (16 lanes/graph) ----------
__global__ __launch_bounds__(256) void k_pool(
    const __half* __restrict__ h, const int* __restrict__ gstart,
    const float* __restrict__ Wl, const float* __restrict__ bl,
    float* __restrict__ out, int G)
{
    int g = (blockIdx.x * blockDim.x + threadIdx.x) >> 4;
    int l = threadIdx.x & 15;
    if (g >= G) return;
    int s = gstart[g], e = gstart[g + 1];
    const uint4* hp = (const uint4*)h + l;
    float acc[8] = {0.f, 0.f, 0.f, 0.f, 0.f, 0.f, 0.f, 0.f};
    for (int n = s; n < e; ++n) {
        float f[8]; unpack8(hp[(size_t)n * 16], f);
#pragma unroll
        for (int i = 0; i < 8; ++i) acc[i] += f[i];
    }
    float inv = 1.0f / fmaxf((float)(e - s), 1.0f);
#pragma unroll
    for (int i = 0; i < 8; ++i) acc[i] *= inv;
    float part = 0.f;
#pragma unroll
    for (int i = 0; i < 8; ++i) part += acc[i];
#pragma unroll
    for (int off = 1; off < 16; off <<= 1) part += __shfl_xor(part, off, 64);
    float mu = part * (1.0f / 128.0f);
    float vpart = 0.f;
#pragma unroll
    for (int i = 0; i < 8; ++i) { float d = acc[i] - mu; vpart += d * d; }
#pragma unroll
    for (int off = 1; off < 16; off <<= 1) vpart += __shfl_xor(vpart, off, 64);
    float r = rsqrtf(vpart * (1.0f / 128.0f) + 1e-5f);
    float4 w0 = *(const float4*)(Wl + l * 8);
    float4 w1 = *(const float4*)(Wl + l * 8 + 4);
    float wv[8] = {w0.x, w0.y, w0.z, w0.w, w1.x, w1.y, w1.z, w1.w};
    float dot = 0.f;
#pragma unroll
    for (int i = 0; i < 8; ++i) dot += (acc[i] - mu) * r * wv[i];
#pragma unroll
    for (int off = 1; off < 16; off <<= 1) dot += __shfl_xor(dot, off, 64);
    if (l == 0) out[g] = dot + bl[0];
}

extern "C" void kernel_launch(void* const* d_in, const int* in_sizes, int n_in,
                              void* d_out, int out_size, void* d_ws, size_t ws_size,
                              hipStream_t stream) {
    const float* x  = (const float*)d_in[0];
    const int* ei   = (const int*)d_in[1];      // [2][E]
    const int* batch = (const int*)d_in[2];
    const float* Ws[5] = {(const float*)d_in[3], (const float*)d_in[5],
                          (const float*)d_in[7], (const float*)d_in[9],
                          (const float*)d_in[11]};
    const float* bs[5] = {(const float*)d_in[4], (const float*)d_in[6],
                          (const float*)d_in[8], (const float*)d_in[10],
                          (const float*)d_in[12]};
    const float* beta1 = (const float*)d_in[13];
    const float* beta2 = (const float*)d_in[14];
    const float* Wl = (const float*)d_in[15];
    const float* bl = (const float*)d_in[16];
    float* out = (float*)d_out;

    int N = in_sizes[0] / 128;
    int E = in_sizes[1] / 2;
    int G = out_size;

    char* ws = (char*)d_ws;
    size_t off = 0;
    auto alloc = [&](size_t bytes) -> void* {
        void* p = ws + off;
        off = (off + bytes + 255) & ~(size_t)255;
        return p;
    };
    __half* aggh = (__half*)alloc((size_t)N * 128 * 2);
    __half* hA   = (__half*)alloc((size_t)N * 128 * 2);
    __half* hB   = (__half*)alloc((size_t)N * 128 * 2);
    int*   deg   = (int*)alloc((size_t)N * 4);
    int*   offs  = (int*)alloc((size_t)(N + 1) * 4);
    int*   rank  = (int*)alloc((size_t)E * 4);
    int*   csr   = (int*)alloc((size_t)(E + N) * 4);
    float* dis   = (float*)alloc((size_t)N * 4);
    float* invn  = (float*)alloc((size_t)N * 4);
    float* invn2 = (float*)alloc((size_t)N * 4);
    int nb = (N + 1023) / 1024;
    int*   part  = (int*)alloc((size_t)nb * 4);
    int*   gst   = (int*)alloc((size_t)(G + 1) * 4);

    // CSR build (atomic-free fill) + pre-scaled x cast
    k_zero_deg<<<(N + 255) / 256, 256, 0, stream>>>(deg, N);
    k_count<<<(E + 255) / 256, 256, 0, stream>>>(ei + E, deg, rank, E);
    k_dis<<<(N + 255) / 256, 256, 0, stream>>>(deg, dis, N);
    k_scan1<<<nb, 256, 0, stream>>>(deg, part, N);
    k_scan2<<<1, 64, 0, stream>>>(part, nb, offs, N);
    k_scan3<<<nb, 256, 0, stream>>>(deg, part, offs, N);
    k_fill_edges<<<(E + 255) / 256, 256, 0, stream>>>(ei, E, offs, rank, csr);
    k_fill_loops<<<(N + 255) / 256, 256, 0, stream>>>(offs, csr, N);
    k_gstart<<<(G + 1 + 255) / 256, 256, 0, stream>>>(batch, N, gst, G);
    k_cast<<<(N * 64 + 255) / 256, 256, 0, stream>>>(x, dis, hA, N * 64);

    int aggBlocks = (N + 15) / 16;   // 16 nodes per 256-thread block
    int gemmBlocks = (N + 31) / 32;

    // 5 GCN layers; layers 0-3 write dis-scaled fp16; layer 4 writes unscaled + invn
    const __half* hin = hA;
    __half* hout = hB;
    for (int l = 0; l < 5; ++l) {
        k_gcn_agg<<<aggBlocks, 256, 0, stream>>>(hin, csr, offs, dis, aggh, N);
        k_gemm_bias_tanh<<<gemmBlocks, 256, 0, stream>>>(
            aggh, Ws[l], bs[l], (l < 4) ? dis : nullptr, hout, N,
            (l == 4) ? invn : nullptr);
        const __half* t = hin; hin = hout; hout = (__half*)t;
    }
    // after loop: hin = h5 (hB), hout = hA
    k_agnn<<<aggBlocks, 256, 0, stream>>>(hin, csr, offs, invn, beta1, hout, N, invn2);
    k_agnn<<<aggBlocks, 256, 0, stream>>>(hout, csr, offs, invn2, beta2, (__half*)hin, N, nullptr);
    k_pool<<<(G + 15) / 16, 256, 0, stream>>>(hin, gst, Wl, bl, out, G);
}